// Round 1
// baseline (2041.390 us; speedup 1.0000x reference)
//
#include <hip/hip_runtime.h>

// R4: spill elimination.
// rocprof showed WRITE_SIZE=2.29GB vs 229KB of real output and FETCH 9x the
// input: ~1.1KB/thread of register-spill scratch round-trips (VGPR_Count=64
// cap from __launch_bounds__(512,4) while stage-2 holds ~70 live floats).
// Changes vs R3:
//   1) __launch_bounds__(512,2): VGPR cap 256 (occupancy is LDS-capped at
//      2 blocks/CU regardless, so the tight reg budget bought nothing).
//   2) Stage 2 restructured: pool window processed as two row-halves, conv
//      pair registers reused across halves. Peak live ~54 floats, fits
//      without spilling even under a conservative allocator.
// Everything else (LDS layout, bf16 activations, per-stage weight staging)
// unchanged from R3.

#define NT 512

// ---- LDS byte offsets ----
// activations
#define O_XS    0        // [6][102][34] bf16 = 41616
#define O_H2S   0        // [16][800]    bf16 = 25600  (xs dead)
#define O_H3S   25600    // [32][80]     bf16 = 5120   -> 30720
#define O_P1S   41616    // [8][52][18]  bf16 = 14976  -> 56592
#define O_P2S   56592    // [16][12][10] bf16 = 3840   -> 60432
#define O_FV    60432    // [256] f32    = 1024        -> 61456
// per-stage weights (fp32), placed in regions dead at that stage
#define O_W1T   61456    // [54][8]   1728 -> 63184   (stage 2)
#define O_B1    63184    //   32 -> 63216
#define O_WP1T  63216    // [4][8][8] 1024 -> 64240
#define O_BP1   64240    //   32 -> 64272
#define O_W2T   25600    // [72][16]  4608 -> 30208   (stage 3)
#define O_B2    30208    //   64 -> 30272
#define O_WP2   41616    // [16][160] 10240 -> 51856  (stage 4)
#define O_BP2   51856    //   64 -> 51920
#define O_W3T   0        // [144][32] 18432 -> 18432  (stage 5)
#define O_B3    18432    //  128 -> 18560
#define O_WP3A  0        // oc 0..15, row stride 324: 20736       (stage 6)
#define O_BP3   20736    //  128 -> 20864
#define O_WP3B  30720    // oc 16..31: 20736 -> 51456
#define O_WMU   0        // [7][256] 7168            (stage 7)
#define O_WLV   7168     // 7168 -> 14336
#define O_BMU   14336    //   28
#define O_BLV   14368    //   28 -> 14396

#define SMEM_BYTES 64288

typedef float f32x8  __attribute__((ext_vector_type(8)));
typedef float f32x16 __attribute__((ext_vector_type(16)));

__device__ __forceinline__ float bf2f(unsigned short u) {
    union { unsigned int i; float f; } v; v.i = ((unsigned int)u) << 16; return v.f;
}
__device__ __forceinline__ float bflo(unsigned int u) {
    union { unsigned int i; float f; } v; v.i = u << 16; return v.f;
}
__device__ __forceinline__ float bfhi(unsigned int u) {
    union { unsigned int i; float f; } v; v.i = u & 0xffff0000u; return v.f;
}
__device__ __forceinline__ unsigned short f2bf(float f) {
    union { float f; unsigned int i; } v; v.f = f;
    unsigned int r = v.i + 0x7FFF + ((v.i >> 16) & 1);   // RNE
    return (unsigned short)(r >> 16);
}
__device__ __forceinline__ float lrelu(float v) { return fmaxf(v, 0.01f * v); }

__device__ __forceinline__ void fma8v(f32x8& a, const float4& wA, const float4& wB, float x) {
    a[0] = __builtin_fmaf(wA.x, x, a[0]); a[1] = __builtin_fmaf(wA.y, x, a[1]);
    a[2] = __builtin_fmaf(wA.z, x, a[2]); a[3] = __builtin_fmaf(wA.w, x, a[3]);
    a[4] = __builtin_fmaf(wB.x, x, a[4]); a[5] = __builtin_fmaf(wB.y, x, a[5]);
    a[6] = __builtin_fmaf(wB.z, x, a[6]); a[7] = __builtin_fmaf(wB.w, x, a[7]);
}
__device__ __forceinline__ void fma16v(f32x16& a, const float4& w0, const float4& w1,
                                       const float4& w2, const float4& w3, float x) {
    a[0]  = __builtin_fmaf(w0.x, x, a[0]);  a[1]  = __builtin_fmaf(w0.y, x, a[1]);
    a[2]  = __builtin_fmaf(w0.z, x, a[2]);  a[3]  = __builtin_fmaf(w0.w, x, a[3]);
    a[4]  = __builtin_fmaf(w1.x, x, a[4]);  a[5]  = __builtin_fmaf(w1.y, x, a[5]);
    a[6]  = __builtin_fmaf(w1.z, x, a[6]);  a[7]  = __builtin_fmaf(w1.w, x, a[7]);
    a[8]  = __builtin_fmaf(w2.x, x, a[8]);  a[9]  = __builtin_fmaf(w2.y, x, a[9]);
    a[10] = __builtin_fmaf(w2.z, x, a[10]); a[11] = __builtin_fmaf(w2.w, x, a[11]);
    a[12] = __builtin_fmaf(w3.x, x, a[12]); a[13] = __builtin_fmaf(w3.y, x, a[13]);
    a[14] = __builtin_fmaf(w3.z, x, a[14]); a[15] = __builtin_fmaf(w3.w, x, a[15]);
}

extern "C" __global__ void __launch_bounds__(512, 2)
vae_encoder_kernel(const float* __restrict__ x,
                   const float* __restrict__ w1,  const float* __restrict__ b1,
                   const float* __restrict__ w2,  const float* __restrict__ b2,
                   const float* __restrict__ w3,  const float* __restrict__ b3,
                   const float* __restrict__ wp1, const float* __restrict__ bp1,
                   const float* __restrict__ wp2, const float* __restrict__ bp2,
                   const float* __restrict__ wp3, const float* __restrict__ bp3,
                   const float* __restrict__ wmu, const float* __restrict__ bmu,
                   const float* __restrict__ wlv, const float* __restrict__ blv,
                   float* __restrict__ out)
{
    __shared__ __align__(16) unsigned char smem[SMEM_BYTES];
    unsigned short* xs  = (unsigned short*)(smem + O_XS);
    unsigned short* h2s = (unsigned short*)(smem + O_H2S);
    unsigned short* h3s = (unsigned short*)(smem + O_H3S);
    unsigned short* p1s = (unsigned short*)(smem + O_P1S);
    unsigned short* p2s = (unsigned short*)(smem + O_P2S);
    float*          fv  = (float*)(smem + O_FV);

    const int tid  = threadIdx.x;
    const int b    = blockIdx.x;
    const int lane = tid & 63;
    const int wave = tid >> 6;

    // ---- 0) zero activation LDS (halo borders must be 0) ----
    for (int i = tid; i < 3841; i += NT)           // 3841*16 = 61456
        ((int4*)smem)[i] = int4{0, 0, 0, 0};
    __syncthreads();

    // ---- 1) load x -> xs (bf16, +1 halo)  +  copy stage-2 weights ----
    {
        const float* xb = x + (size_t)b * 19200;
        for (int i = tid; i < 4800; i += NT) {
            float4 v = ((const float4*)xb)[i];
            int c   = i / 800;
            int rem = i - c * 800;
            int row = rem >> 3;
            int c4  = rem & 7;
            int base = c * 3468 + (row + 1) * 34 + (c4 * 4 + 1);
            xs[base + 0] = f2bf(v.x); xs[base + 1] = f2bf(v.y);
            xs[base + 2] = f2bf(v.z); xs[base + 3] = f2bf(v.w);
        }
        float* w1t  = (float*)(smem + O_W1T);
        float* b1s  = (float*)(smem + O_B1);
        float* wp1t = (float*)(smem + O_WP1T);
        float* bp1s = (float*)(smem + O_BP1);
        for (int i = tid; i < 432; i += NT) {      // w1t[r][o] = w1[o][r]
            int o = i & 7, r = i >> 3;
            w1t[i] = w1[o * 54 + r];
        }
        for (int i = tid; i < 256; i += NT) {      // wp1t[k][ic][o] = wp1[o][ic][k]
            int o = i & 7, ic = (i >> 3) & 7, k = i >> 6;
            wp1t[i] = wp1[(o * 8 + ic) * 4 + k];
        }
        if (tid < 8)  b1s[tid]  = b1[tid];
        if (tid < 8)  bp1s[tid] = bp1[tid];
    }
    __syncthreads();

    // ---- 2) conv1(3x3,6->8)+lrelu fused with pool1(2x2/2,8->8) -> p1s ----
    // Restructured vs R3: two row-half passes over the 2x2 pool window so the
    // conv pair registers (h0,h1) are reused; peak live set ~54 floats.
    {
        const float* w1s  = (const float*)(smem + O_W1T);
        const float* b1s  = (const float*)(smem + O_B1);
        const float* wp1s = (const float*)(smem + O_WP1T);
        const float* bp1s = (const float*)(smem + O_BP1);
        #pragma unroll 1
        for (int pos = tid; pos < 800; pos += NT) {
            const int pr = pos >> 4, pc = pos & 15;
            const int row0 = 2 * pr, col0 = 2 * pc;   // padded coords
            f32x8 acc;
            {
                float4 bA = *(const float4*)&bp1s[0];
                float4 bB = *(const float4*)&bp1s[4];
                acc[0]=bA.x; acc[1]=bA.y; acc[2]=bA.z; acc[3]=bA.w;
                acc[4]=bB.x; acc[5]=bB.y; acc[6]=bB.z; acc[7]=bB.w;
            }
            #pragma unroll
            for (int half = 0; half < 2; half++) {
                f32x8 h0, h1;
                {
                    float4 bA = *(const float4*)&b1s[0];
                    float4 bB = *(const float4*)&b1s[4];
                    h0[0]=bA.x; h0[1]=bA.y; h0[2]=bA.z; h0[3]=bA.w;
                    h0[4]=bB.x; h0[5]=bB.y; h0[6]=bB.z; h0[7]=bB.w;
                    h1 = h0;
                }
                #pragma unroll 1
                for (int c = 0; c < 6; c++) {
                    float xw[12];
                    #pragma unroll
                    for (int i = 0; i < 3; i++) {
                        const unsigned int* rp =
                            (const unsigned int*)&xs[c * 3468 + (row0 + half + i) * 34 + col0];
                        unsigned int u0 = rp[0], u1 = rp[1];
                        xw[i*4+0] = bflo(u0); xw[i*4+1] = bfhi(u0);
                        xw[i*4+2] = bflo(u1); xw[i*4+3] = bfhi(u1);
                    }
                    #pragma unroll
                    for (int dy = 0; dy < 3; dy++)
                        #pragma unroll
                        for (int dx = 0; dx < 3; dx++) {
                            const float* wg = &w1s[(c * 9 + dy * 3 + dx) * 8];
                            float4 wA = *(const float4*)&wg[0];
                            float4 wB = *(const float4*)&wg[4];
                            fma8v(h0, wA, wB, xw[dy*4+dx]);
                            fma8v(h1, wA, wB, xw[dy*4+dx+1]);
                        }
                }
                // pool taps for this row-half: k = 2*half (kw=0), 2*half+1 (kw=1)
                #pragma unroll
                for (int ic = 0; ic < 8; ic++) {
                    float v0 = lrelu(h0[ic]);
                    float v1 = lrelu(h1[ic]);
                    const float* g0 = &wp1s[((2 * half + 0) * 8 + ic) * 8];
                    const float* g1 = &wp1s[((2 * half + 1) * 8 + ic) * 8];
                    fma8v(acc, *(const float4*)&g0[0], *(const float4*)&g0[4], v0);
                    fma8v(acc, *(const float4*)&g1[0], *(const float4*)&g1[4], v1);
                }
            }
            #pragma unroll
            for (int o = 0; o < 8; o++)
                p1s[o * 936 + (pr + 1) * 18 + (pc + 1)] = f2bf(acc[o]);
        }
    }
    __syncthreads();

    // ---- copy stage-3 weights (w2 transposed) ----
    {
        float* w2t = (float*)(smem + O_W2T);
        float* b2s = (float*)(smem + O_B2);
        for (int i = tid; i < 1152; i += NT) {     // w2t[r][o] = w2[o][r]
            int o = i & 15, r = i >> 4;
            w2t[i] = w2[o * 72 + r];
        }
        if (tid < 16) b2s[tid] = b2[tid];
    }
    __syncthreads();

    // ---- 3) conv2(3x3,8->16)+lrelu -> h2s ----
    {
        const float* w2s = (const float*)(smem + O_W2T);
        const float* b2s = (const float*)(smem + O_B2);
        #pragma unroll 1
        for (int pos = tid; pos < 800; pos += NT) {
            const int r = pos >> 4, c = pos & 15;
            f32x16 acc;
            {
                float4 b0 = *(const float4*)&b2s[0];
                float4 b1v = *(const float4*)&b2s[4];
                float4 b2v = *(const float4*)&b2s[8];
                float4 b3v = *(const float4*)&b2s[12];
                acc[0]=b0.x;  acc[1]=b0.y;  acc[2]=b0.z;  acc[3]=b0.w;
                acc[4]=b1v.x; acc[5]=b1v.y; acc[6]=b1v.z; acc[7]=b1v.w;
                acc[8]=b2v.x; acc[9]=b2v.y; acc[10]=b2v.z; acc[11]=b2v.w;
                acc[12]=b3v.x; acc[13]=b3v.y; acc[14]=b3v.z; acc[15]=b3v.w;
            }
            #pragma unroll 1
            for (int ic = 0; ic < 8; ic++) {
                float xw[9];
                #pragma unroll
                for (int dy = 0; dy < 3; dy++) {
                    int base = ic * 936 + (r + dy) * 18 + c;
                    xw[dy*3+0] = bf2f(p1s[base + 0]);
                    xw[dy*3+1] = bf2f(p1s[base + 1]);
                    xw[dy*3+2] = bf2f(p1s[base + 2]);
                }
                #pragma unroll
                for (int k = 0; k < 9; k++) {
                    const float* wg = &w2s[(ic * 9 + k) * 16];
                    fma16v(acc, *(const float4*)&wg[0], *(const float4*)&wg[4],
                           *(const float4*)&wg[8], *(const float4*)&wg[12], xw[k]);
                }
            }
            #pragma unroll
            for (int o = 0; o < 16; o++)
                h2s[o * 800 + pos] = f2bf(lrelu(acc[o]));
        }
    }
    __syncthreads();

    // ---- copy stage-4 weights (wp2 plain) ----
    {
        float* wp2s = (float*)(smem + O_WP2);
        float* bp2s = (float*)(smem + O_BP2);
        for (int i = tid; i < 2560; i += NT) wp2s[i] = wp2[i];
        if (tid < 16) bp2s[tid] = bp2[tid];
    }
    __syncthreads();

    // ---- 4) pool2 (5x2 / (5,2), 16->16) -> p2s ----
    {
        const float* wp2s = (const float*)(smem + O_WP2);
        const float* bp2s = (const float*)(smem + O_BP2);
        const int oc0 = wave;                       // 0..7, handles oc0 & oc0+8
        #pragma unroll 1
        for (int pos = lane; pos < 80; pos += 64) {
            const int pr = pos >> 3, pc = pos & 7;
            float a0 = bp2s[oc0], a1 = bp2s[oc0 + 8];
            #pragma unroll 1
            for (int ic = 0; ic < 16; ic++) {
                float xv[10];
                #pragma unroll
                for (int kh = 0; kh < 5; kh++) {
                    unsigned int u = *(const unsigned int*)
                        &h2s[ic * 800 + (5 * pr + kh) * 16 + 2 * pc];
                    xv[kh*2+0] = bflo(u); xv[kh*2+1] = bfhi(u);
                }
                const float* wr0 = &wp2s[oc0 * 160 + ic * 10];
                const float* wr1 = &wp2s[(oc0 + 8) * 160 + ic * 10];
                #pragma unroll
                for (int k = 0; k < 10; k++) {
                    a0 = __builtin_fmaf(wr0[k], xv[k], a0);
                    a1 = __builtin_fmaf(wr1[k], xv[k], a1);
                }
            }
            p2s[oc0 * 120 + (pr + 1) * 10 + (pc + 1)]       = f2bf(a0);
            p2s[(oc0 + 8) * 120 + (pr + 1) * 10 + (pc + 1)] = f2bf(a1);
        }
    }
    __syncthreads();

    // ---- copy stage-5 weights (w3 transposed) ----
    {
        float* w3t = (float*)(smem + O_W3T);
        float* b3s = (float*)(smem + O_B3);
        for (int i = tid; i < 4608; i += NT) {     // w3t[r][o] = w3[o][r]
            int o = i & 31, r = i >> 5;
            w3t[i] = w3[o * 144 + r];
        }
        if (tid < 32) b3s[tid] = b3[tid];
    }
    __syncthreads();

    // ---- 5) conv3(3x3,16->32)+lrelu -> h3s ----
    {
        const float* w3s = (const float*)(smem + O_W3T);
        const float* b3s = (const float*)(smem + O_B3);
        const int ocg = wave;                       // 4 oc per wave
        #pragma unroll 1
        for (int pos = lane; pos < 80; pos += 64) {
            const int r = pos >> 3, cc = pos & 7;
            float4 bv = *(const float4*)&b3s[ocg * 4];
            float a0 = bv.x, a1 = bv.y, a2 = bv.z, a3 = bv.w;
            #pragma unroll 1
            for (int ic = 0; ic < 16; ic++) {
                float xw[9];
                #pragma unroll
                for (int dy = 0; dy < 3; dy++) {
                    int base = ic * 120 + (r + dy) * 10 + cc;
                    xw[dy*3+0] = bf2f(p2s[base + 0]);
                    xw[dy*3+1] = bf2f(p2s[base + 1]);
                    xw[dy*3+2] = bf2f(p2s[base + 2]);
                }
                #pragma unroll
                for (int k = 0; k < 9; k++) {
                    float4 w = *(const float4*)&w3s[(ic * 9 + k) * 32 + ocg * 4];
                    a0 = __builtin_fmaf(w.x, xw[k], a0);
                    a1 = __builtin_fmaf(w.y, xw[k], a1);
                    a2 = __builtin_fmaf(w.z, xw[k], a2);
                    a3 = __builtin_fmaf(w.w, xw[k], a3);
                }
            }
            h3s[(ocg*4+0)*80 + pos] = f2bf(lrelu(a0));
            h3s[(ocg*4+1)*80 + pos] = f2bf(lrelu(a1));
            h3s[(ocg*4+2)*80 + pos] = f2bf(lrelu(a2));
            h3s[(ocg*4+3)*80 + pos] = f2bf(lrelu(a3));
        }
    }
    __syncthreads();

    // ---- copy stage-6 weights (wp3, row stride 324 to spread banks) ----
    {
        float* wA = (float*)(smem + O_WP3A);
        float* wB = (float*)(smem + O_WP3B);
        float* bp3s = (float*)(smem + O_BP3);
        for (int oc = wave; oc < 32; oc += 8) {
            float* dst = (oc < 16) ? (wA + oc * 324) : (wB + (oc - 16) * 324);
            const float* src = wp3 + oc * 320;
            for (int j = lane; j < 320; j += 64) dst[j] = src[j];
        }
        if (tid < 32) bp3s[tid] = bp3[tid];
    }
    __syncthreads();

    // ---- 6) pool3 (5x2 / (5,2), 32->32) -> fv[256] ----
    {
        const float* bp3s = (const float*)(smem + O_BP3);
        if (tid < 256) {
            const int oc = tid >> 3, pos = tid & 7;
            const int pr = pos >> 2, pc = pos & 3;
            const float* wrow = (oc < 16)
                ? (const float*)(smem + O_WP3A) + oc * 324
                : (const float*)(smem + O_WP3B) + (oc - 16) * 324;
            float a = bp3s[oc];
            #pragma unroll 1
            for (int ic = 0; ic < 32; ic++) {
                float xv[10];
                #pragma unroll
                for (int kh = 0; kh < 5; kh++) {
                    unsigned int u = *(const unsigned int*)
                        &h3s[ic * 80 + (5 * pr + kh) * 8 + 2 * pc];
                    xv[kh*2+0] = bflo(u); xv[kh*2+1] = bfhi(u);
                }
                #pragma unroll
                for (int k = 0; k < 10; k++)
                    a = __builtin_fmaf(wrow[ic * 10 + k], xv[k], a);
            }
            fv[oc * 8 + pos] = a;                   // flatten [32][2][4]
        }
    }
    __syncthreads();

    // ---- copy stage-7 weights ----
    {
        float* wmus = (float*)(smem + O_WMU);
        float* wlvs = (float*)(smem + O_WLV);
        float* bmus = (float*)(smem + O_BMU);
        float* blvs = (float*)(smem + O_BLV);
        for (int i = tid; i < 1792; i += NT) wmus[i] = wmu[i];
        for (int i = tid; i < 1792; i += NT) wlvs[i] = wlv[i];
        if (tid < 7) bmus[tid] = bmu[tid];
        if (tid < 7) blvs[tid] = blv[tid];
    }
    __syncthreads();

    // ---- 7) heads ----
    {
        const float* wmus = (const float*)(smem + O_WMU);
        const float* wlvs = (const float*)(smem + O_WLV);
        const float* bmus = (const float*)(smem + O_BMU);
        const float* blvs = (const float*)(smem + O_BLV);
        if (wave < 7) {
            const int j = wave;
            #pragma unroll
            for (int head = 0; head < 2; head++) {
                const float* W = head ? wlvs : wmus;
                float s = 0.f;
                #pragma unroll
                for (int q = 0; q < 4; q++) {
                    int k = lane + 64 * q;
                    s = __builtin_fmaf(fv[k], W[j * 256 + k], s);
                }
                #pragma unroll
                for (int m = 1; m < 64; m <<= 1) s += __shfl_xor(s, m);
                if (lane == 0) {
                    float r = s + (head ? blvs[j] : bmus[j]);
                    if (head) r = fminf(fmaxf(r, -5.f), 0.f);
                    out[head * 28672 + b * 7 + j] = r;
                }
            }
        }
    }
}

extern "C" void kernel_launch(void* const* d_in, const int* in_sizes, int n_in,
                              void* d_out, int out_size, void* d_ws, size_t ws_size,
                              hipStream_t stream) {
    const float* x   = (const float*)d_in[0];
    const float* w1  = (const float*)d_in[1];
    const float* b1  = (const float*)d_in[2];
    const float* w2  = (const float*)d_in[3];
    const float* b2  = (const float*)d_in[4];
    const float* w3  = (const float*)d_in[5];
    const float* b3  = (const float*)d_in[6];
    const float* wp1 = (const float*)d_in[7];
    const float* bp1 = (const float*)d_in[8];
    const float* wp2 = (const float*)d_in[9];
    const float* bp2 = (const float*)d_in[10];
    const float* wp3 = (const float*)d_in[11];
    const float* bp3 = (const float*)d_in[12];
    const float* wmu = (const float*)d_in[13];
    const float* bmu = (const float*)d_in[14];
    const float* wlv = (const float*)d_in[15];
    const float* blv = (const float*)d_in[16];
    float* out = (float*)d_out;

    hipLaunchKernelGGL(vae_encoder_kernel, dim3(4096), dim3(512), 0, stream,
                       x, w1, b1, w2, b2, w3, b3, wp1, bp1, wp2, bp2, wp3, bp3,
                       wmu, bmu, wlv, blv, out);
}

// Round 2
// 989.547 us; speedup vs baseline: 2.0630x; 2.0630x over previous
//
#include <hip/hip_runtime.h>

// R5: scratch/localMem elimination.
// R4 falsified the "VGPR-cap spill" theory: VGPR 64->128 yet WRITE_SIZE stayed
// 2.1GB. Remaining mechanism: local arrays (xw[12]/xw[9]/xv[10]) demoted to
// scratch (rule #20 class), invisible in VGPR_Count. This version has ZERO
// local arrays: all activation taps are named scalars read straight from LDS
// with literal offsets; all ext_vector accesses use literal indices via
// hand-unrolled macros. launch_bounds back to (512,4) for 2 blocks/CU.

#define NT 512

// ---- LDS byte offsets ----
#define O_XS    0        // [6][102][34] bf16 = 41616
#define O_H2S   0        // [16][800]    bf16 = 25600  (xs dead)
#define O_H3S   25600    // [32][80]     bf16 = 5120   -> 30720
#define O_P1S   41616    // [8][52][18]  bf16 = 14976  -> 56592
#define O_P2S   56592    // [16][12][10] bf16 = 3840   -> 60432
#define O_FV    60432    // [256] f32    = 1024        -> 61456
#define O_W1T   61456    // [54][8]   1728 -> 63184   (stage 2)
#define O_B1    63184    //   32 -> 63216
#define O_WP1T  63216    // [4][8][8] 1024 -> 64240
#define O_BP1   64240    //   32 -> 64272
#define O_W2T   25600    // [72][16]  4608 -> 30208   (stage 3)
#define O_B2    30208    //   64 -> 30272
#define O_WP2   41616    // [16][160] 10240 -> 51856  (stage 4)
#define O_BP2   51856    //   64 -> 51920
#define O_W3T   0        // [144][32] 18432 -> 18432  (stage 5)
#define O_B3    18432    //  128 -> 18560
#define O_WP3A  0        // oc 0..15, row stride 324: 20736       (stage 6)
#define O_BP3   20736    //  128 -> 20864
#define O_WP3B  30720    // oc 16..31: 20736 -> 51456
#define O_WMU   0        // [7][256] 7168            (stage 7)
#define O_WLV   7168     // 7168 -> 14336
#define O_BMU   14336    //   28
#define O_BLV   14368    //   28 -> 14396

#define SMEM_BYTES 64288

typedef float f32x8  __attribute__((ext_vector_type(8)));
typedef float f32x16 __attribute__((ext_vector_type(16)));

__device__ __forceinline__ float bf2f(unsigned short u) {
    union { unsigned int i; float f; } v; v.i = ((unsigned int)u) << 16; return v.f;
}
__device__ __forceinline__ float bflo(unsigned int u) {
    union { unsigned int i; float f; } v; v.i = u << 16; return v.f;
}
__device__ __forceinline__ float bfhi(unsigned int u) {
    union { unsigned int i; float f; } v; v.i = u & 0xffff0000u; return v.f;
}
__device__ __forceinline__ unsigned short f2bf(float f) {
    union { float f; unsigned int i; } v; v.f = f;
    unsigned int r = v.i + 0x7FFF + ((v.i >> 16) & 1);   // RNE
    return (unsigned short)(r >> 16);
}
__device__ __forceinline__ float lrelu(float v) { return fmaxf(v, 0.01f * v); }

#define LD4(p) (*(const float4*)(p))

__device__ __forceinline__ void fma8v(f32x8& a, const float4& wA, const float4& wB, float x) {
    a[0] = __builtin_fmaf(wA.x, x, a[0]); a[1] = __builtin_fmaf(wA.y, x, a[1]);
    a[2] = __builtin_fmaf(wA.z, x, a[2]); a[3] = __builtin_fmaf(wA.w, x, a[3]);
    a[4] = __builtin_fmaf(wB.x, x, a[4]); a[5] = __builtin_fmaf(wB.y, x, a[5]);
    a[6] = __builtin_fmaf(wB.z, x, a[6]); a[7] = __builtin_fmaf(wB.w, x, a[7]);
}
__device__ __forceinline__ void fma16v(f32x16& a, const float4& w0, const float4& w1,
                                       const float4& w2, const float4& w3, float x) {
    a[0]  = __builtin_fmaf(w0.x, x, a[0]);  a[1]  = __builtin_fmaf(w0.y, x, a[1]);
    a[2]  = __builtin_fmaf(w0.z, x, a[2]);  a[3]  = __builtin_fmaf(w0.w, x, a[3]);
    a[4]  = __builtin_fmaf(w1.x, x, a[4]);  a[5]  = __builtin_fmaf(w1.y, x, a[5]);
    a[6]  = __builtin_fmaf(w1.z, x, a[6]);  a[7]  = __builtin_fmaf(w1.w, x, a[7]);
    a[8]  = __builtin_fmaf(w2.x, x, a[8]);  a[9]  = __builtin_fmaf(w2.y, x, a[9]);
    a[10] = __builtin_fmaf(w2.z, x, a[10]); a[11] = __builtin_fmaf(w2.w, x, a[11]);
    a[12] = __builtin_fmaf(w3.x, x, a[12]); a[13] = __builtin_fmaf(w3.y, x, a[13]);
    a[14] = __builtin_fmaf(w3.z, x, a[14]); a[15] = __builtin_fmaf(w3.w, x, a[15]);
}

extern "C" __global__ void __launch_bounds__(512, 4)
vae_encoder_kernel(const float* __restrict__ x,
                   const float* __restrict__ w1,  const float* __restrict__ b1,
                   const float* __restrict__ w2,  const float* __restrict__ b2,
                   const float* __restrict__ w3,  const float* __restrict__ b3,
                   const float* __restrict__ wp1, const float* __restrict__ bp1,
                   const float* __restrict__ wp2, const float* __restrict__ bp2,
                   const float* __restrict__ wp3, const float* __restrict__ bp3,
                   const float* __restrict__ wmu, const float* __restrict__ bmu,
                   const float* __restrict__ wlv, const float* __restrict__ blv,
                   float* __restrict__ out)
{
    __shared__ __align__(16) unsigned char smem[SMEM_BYTES];
    unsigned short* xs  = (unsigned short*)(smem + O_XS);
    unsigned short* h2s = (unsigned short*)(smem + O_H2S);
    unsigned short* h3s = (unsigned short*)(smem + O_H3S);
    unsigned short* p1s = (unsigned short*)(smem + O_P1S);
    unsigned short* p2s = (unsigned short*)(smem + O_P2S);
    float*          fv  = (float*)(smem + O_FV);

    const int tid  = threadIdx.x;
    const int b    = blockIdx.x;
    const int lane = tid & 63;
    const int wave = tid >> 6;

    // ---- 0) zero activation LDS (halo borders must be 0) ----
    for (int i = tid; i < 3841; i += NT)           // 3841*16 = 61456
        ((int4*)smem)[i] = int4{0, 0, 0, 0};
    __syncthreads();

    // ---- 1) load x -> xs (bf16, +1 halo)  +  copy stage-2 weights ----
    {
        const float* xb = x + (size_t)b * 19200;
        for (int i = tid; i < 4800; i += NT) {
            float4 v = ((const float4*)xb)[i];
            int c   = i / 800;
            int rem = i - c * 800;
            int row = rem >> 3;
            int c4  = rem & 7;
            int base = c * 3468 + (row + 1) * 34 + (c4 * 4 + 1);
            xs[base + 0] = f2bf(v.x); xs[base + 1] = f2bf(v.y);
            xs[base + 2] = f2bf(v.z); xs[base + 3] = f2bf(v.w);
        }
        float* w1t  = (float*)(smem + O_W1T);
        float* b1s  = (float*)(smem + O_B1);
        float* wp1t = (float*)(smem + O_WP1T);
        float* bp1s = (float*)(smem + O_BP1);
        for (int i = tid; i < 432; i += NT) {      // w1t[r][o] = w1[o][r]
            int o = i & 7, r = i >> 3;
            w1t[i] = w1[o * 54 + r];
        }
        for (int i = tid; i < 256; i += NT) {      // wp1t[k][ic][o] = wp1[o][ic][k]
            int o = i & 7, ic = (i >> 3) & 7, k = i >> 6;
            wp1t[i] = wp1[(o * 8 + ic) * 4 + k];
        }
        if (tid < 8)  b1s[tid]  = b1[tid];
        if (tid < 8)  bp1s[tid] = bp1[tid];
    }
    __syncthreads();

    // ---- 2) conv1(3x3,6->8)+lrelu fused with pool1(2x2/2,8->8) -> p1s ----
    // No local arrays: taps are named scalars, literal LDS offsets.
    {
        const float* w1s  = (const float*)(smem + O_W1T);
        const float* b1s  = (const float*)(smem + O_B1);
        const float* wp1s = (const float*)(smem + O_WP1T);
        const float* bp1s = (const float*)(smem + O_BP1);

// one conv row (dy): 3 taps feeding the h0/h1 column pair
#define C1ROW(u0, u1, W) do {                                        \
    float xa_ = bflo(u0), xb_ = bfhi(u0);                            \
    float xc_ = bflo(u1), xd_ = bfhi(u1);                            \
    fma8v(h0, LD4((W)+0),  LD4((W)+4),  xa_);                        \
    fma8v(h1, LD4((W)+0),  LD4((W)+4),  xb_);                        \
    fma8v(h0, LD4((W)+8),  LD4((W)+12), xb_);                        \
    fma8v(h1, LD4((W)+8),  LD4((W)+12), xc_);                        \
    fma8v(h0, LD4((W)+16), LD4((W)+20), xc_);                        \
    fma8v(h1, LD4((W)+16), LD4((W)+20), xd_);                        \
} while (0)

#define POOL1(ic) do {                                               \
    float v0_ = lrelu(h0[ic]); float v1_ = lrelu(h1[ic]);            \
    const float* g0_ = &wp1s[(k0 * 8 + (ic)) * 8];                   \
    const float* g1_ = &wp1s[(k1 * 8 + (ic)) * 8];                   \
    fma8v(acc, LD4(g0_), LD4(g0_ + 4), v0_);                         \
    fma8v(acc, LD4(g1_), LD4(g1_ + 4), v1_);                         \
} while (0)

        #pragma unroll 1
        for (int pos = tid; pos < 800; pos += NT) {
            const int pr = pos >> 4, pc = pos & 15;
            const int row0 = 2 * pr, col0 = 2 * pc;   // padded coords
            f32x8 acc;
            {
                float4 bA = LD4(&bp1s[0]);
                float4 bB = LD4(&bp1s[4]);
                acc[0]=bA.x; acc[1]=bA.y; acc[2]=bA.z; acc[3]=bA.w;
                acc[4]=bB.x; acc[5]=bB.y; acc[6]=bB.z; acc[7]=bB.w;
            }
            #pragma unroll 1
            for (int half = 0; half < 2; half++) {
                const int k0 = 2 * half, k1 = 2 * half + 1;
                f32x8 h0, h1;
                {
                    float4 bA = LD4(&b1s[0]);
                    float4 bB = LD4(&b1s[4]);
                    h0[0]=bA.x; h0[1]=bA.y; h0[2]=bA.z; h0[3]=bA.w;
                    h0[4]=bB.x; h0[5]=bB.y; h0[6]=bB.z; h0[7]=bB.w;
                    h1 = h0;
                }
                #pragma unroll 1
                for (int c = 0; c < 6; c++) {
                    const unsigned short* rb =
                        &xs[c * 3468 + (row0 + half) * 34 + col0];
                    unsigned int u00 = *(const unsigned int*)(rb + 0);
                    unsigned int u01 = *(const unsigned int*)(rb + 2);
                    unsigned int u10 = *(const unsigned int*)(rb + 34);
                    unsigned int u11 = *(const unsigned int*)(rb + 36);
                    unsigned int u20 = *(const unsigned int*)(rb + 68);
                    unsigned int u21 = *(const unsigned int*)(rb + 70);
                    const float* wc = &w1s[c * 72];
                    C1ROW(u00, u01, wc + 0);
                    C1ROW(u10, u11, wc + 24);
                    C1ROW(u20, u21, wc + 48);
                }
                POOL1(0); POOL1(1); POOL1(2); POOL1(3);
                POOL1(4); POOL1(5); POOL1(6); POOL1(7);
            }
            {
                const int pb = (pr + 1) * 18 + (pc + 1);
                p1s[0 * 936 + pb] = f2bf(acc[0]);
                p1s[1 * 936 + pb] = f2bf(acc[1]);
                p1s[2 * 936 + pb] = f2bf(acc[2]);
                p1s[3 * 936 + pb] = f2bf(acc[3]);
                p1s[4 * 936 + pb] = f2bf(acc[4]);
                p1s[5 * 936 + pb] = f2bf(acc[5]);
                p1s[6 * 936 + pb] = f2bf(acc[6]);
                p1s[7 * 936 + pb] = f2bf(acc[7]);
            }
        }
#undef C1ROW
#undef POOL1
    }
    __syncthreads();

    // ---- copy stage-3 weights (w2 transposed) ----
    {
        float* w2t = (float*)(smem + O_W2T);
        float* b2s = (float*)(smem + O_B2);
        for (int i = tid; i < 1152; i += NT) {     // w2t[r][o] = w2[o][r]
            int o = i & 15, r = i >> 4;
            w2t[i] = w2[o * 72 + r];
        }
        if (tid < 16) b2s[tid] = b2[tid];
    }
    __syncthreads();

    // ---- 3) conv2(3x3,8->16)+lrelu -> h2s ----
    {
        const float* w2s = (const float*)(smem + O_W2T);
        const float* b2s = (const float*)(smem + O_B2);

#define T3(k, xv) fma16v(acc, LD4(wg + (k)*16), LD4(wg + (k)*16 + 4), \
                         LD4(wg + (k)*16 + 8), LD4(wg + (k)*16 + 12), (xv))

        #pragma unroll 1
        for (int pos = tid; pos < 800; pos += NT) {
            const int r = pos >> 4, c = pos & 15;
            f32x16 acc;
            {
                float4 b0 = LD4(&b2s[0]);
                float4 b1v = LD4(&b2s[4]);
                float4 b2v = LD4(&b2s[8]);
                float4 b3v = LD4(&b2s[12]);
                acc[0]=b0.x;  acc[1]=b0.y;  acc[2]=b0.z;  acc[3]=b0.w;
                acc[4]=b1v.x; acc[5]=b1v.y; acc[6]=b1v.z; acc[7]=b1v.w;
                acc[8]=b2v.x; acc[9]=b2v.y; acc[10]=b2v.z; acc[11]=b2v.w;
                acc[12]=b3v.x; acc[13]=b3v.y; acc[14]=b3v.z; acc[15]=b3v.w;
            }
            #pragma unroll 1
            for (int ic = 0; ic < 8; ic++) {
                const unsigned short* rb = &p1s[ic * 936 + r * 18 + c];
                float x00 = bf2f(rb[0]),  x01 = bf2f(rb[1]),  x02 = bf2f(rb[2]);
                float x10 = bf2f(rb[18]), x11 = bf2f(rb[19]), x12 = bf2f(rb[20]);
                float x20 = bf2f(rb[36]), x21 = bf2f(rb[37]), x22 = bf2f(rb[38]);
                const float* wg = &w2s[ic * 144];
                T3(0, x00); T3(1, x01); T3(2, x02);
                T3(3, x10); T3(4, x11); T3(5, x12);
                T3(6, x20); T3(7, x21); T3(8, x22);
            }
            h2s[0  * 800 + pos] = f2bf(lrelu(acc[0]));
            h2s[1  * 800 + pos] = f2bf(lrelu(acc[1]));
            h2s[2  * 800 + pos] = f2bf(lrelu(acc[2]));
            h2s[3  * 800 + pos] = f2bf(lrelu(acc[3]));
            h2s[4  * 800 + pos] = f2bf(lrelu(acc[4]));
            h2s[5  * 800 + pos] = f2bf(lrelu(acc[5]));
            h2s[6  * 800 + pos] = f2bf(lrelu(acc[6]));
            h2s[7  * 800 + pos] = f2bf(lrelu(acc[7]));
            h2s[8  * 800 + pos] = f2bf(lrelu(acc[8]));
            h2s[9  * 800 + pos] = f2bf(lrelu(acc[9]));
            h2s[10 * 800 + pos] = f2bf(lrelu(acc[10]));
            h2s[11 * 800 + pos] = f2bf(lrelu(acc[11]));
            h2s[12 * 800 + pos] = f2bf(lrelu(acc[12]));
            h2s[13 * 800 + pos] = f2bf(lrelu(acc[13]));
            h2s[14 * 800 + pos] = f2bf(lrelu(acc[14]));
            h2s[15 * 800 + pos] = f2bf(lrelu(acc[15]));
        }
#undef T3
    }
    __syncthreads();

    // ---- copy stage-4 weights (wp2 plain) ----
    {
        float* wp2s = (float*)(smem + O_WP2);
        float* bp2s = (float*)(smem + O_BP2);
        for (int i = tid; i < 2560; i += NT) wp2s[i] = wp2[i];
        if (tid < 16) bp2s[tid] = bp2[tid];
    }
    __syncthreads();

    // ---- 4) pool2 (5x2 / (5,2), 16->16) -> p2s ----
    {
        const float* wp2s = (const float*)(smem + O_WP2);
        const float* bp2s = (const float*)(smem + O_BP2);
        const int oc0 = wave;                       // 0..7, handles oc0 & oc0+8

#define T4(k, xv) do { float xv_ = (xv);                              \
    a0 = __builtin_fmaf(wr0[k], xv_, a0);                             \
    a1 = __builtin_fmaf(wr1[k], xv_, a1); } while (0)

        #pragma unroll 1
        for (int pos = lane; pos < 80; pos += 64) {
            const int pr = pos >> 3, pc = pos & 7;
            float a0 = bp2s[oc0], a1 = bp2s[oc0 + 8];
            #pragma unroll 1
            for (int ic = 0; ic < 16; ic++) {
                const unsigned short* hb = &h2s[ic * 800 + 5 * pr * 16 + 2 * pc];
                unsigned int u0 = *(const unsigned int*)(hb + 0);
                unsigned int u1 = *(const unsigned int*)(hb + 16);
                unsigned int u2 = *(const unsigned int*)(hb + 32);
                unsigned int u3 = *(const unsigned int*)(hb + 48);
                unsigned int u4 = *(const unsigned int*)(hb + 64);
                const float* wr0 = &wp2s[oc0 * 160 + ic * 10];
                const float* wr1 = &wp2s[(oc0 + 8) * 160 + ic * 10];
                T4(0, bflo(u0)); T4(1, bfhi(u0));
                T4(2, bflo(u1)); T4(3, bfhi(u1));
                T4(4, bflo(u2)); T4(5, bfhi(u2));
                T4(6, bflo(u3)); T4(7, bfhi(u3));
                T4(8, bflo(u4)); T4(9, bfhi(u4));
            }
            p2s[oc0 * 120 + (pr + 1) * 10 + (pc + 1)]       = f2bf(a0);
            p2s[(oc0 + 8) * 120 + (pr + 1) * 10 + (pc + 1)] = f2bf(a1);
        }
#undef T4
    }
    __syncthreads();

    // ---- copy stage-5 weights (w3 transposed) ----
    {
        float* w3t = (float*)(smem + O_W3T);
        float* b3s = (float*)(smem + O_B3);
        for (int i = tid; i < 4608; i += NT) {     // w3t[r][o] = w3[o][r]
            int o = i & 31, r = i >> 5;
            w3t[i] = w3[o * 144 + r];
        }
        if (tid < 32) b3s[tid] = b3[tid];
    }
    __syncthreads();

    // ---- 5) conv3(3x3,16->32)+lrelu -> h3s ----
    {
        const float* w3s = (const float*)(smem + O_W3T);
        const float* b3s = (const float*)(smem + O_B3);
        const int ocg = wave;                       // 4 oc per wave

#define T5(k, xv) do { float4 w_ = LD4(wg + (k) * 32);                \
    float xv_ = (xv);                                                 \
    a0 = __builtin_fmaf(w_.x, xv_, a0);                               \
    a1 = __builtin_fmaf(w_.y, xv_, a1);                               \
    a2 = __builtin_fmaf(w_.z, xv_, a2);                               \
    a3 = __builtin_fmaf(w_.w, xv_, a3); } while (0)

        #pragma unroll 1
        for (int pos = lane; pos < 80; pos += 64) {
            const int r = pos >> 3, cc = pos & 7;
            float4 bv = LD4(&b3s[ocg * 4]);
            float a0 = bv.x, a1 = bv.y, a2 = bv.z, a3 = bv.w;
            #pragma unroll 1
            for (int ic = 0; ic < 16; ic++) {
                const unsigned short* rb = &p2s[ic * 120 + r * 10 + cc];
                float x00 = bf2f(rb[0]),  x01 = bf2f(rb[1]),  x02 = bf2f(rb[2]);
                float x10 = bf2f(rb[10]), x11 = bf2f(rb[11]), x12 = bf2f(rb[12]);
                float x20 = bf2f(rb[20]), x21 = bf2f(rb[21]), x22 = bf2f(rb[22]);
                const float* wg = &w3s[ic * 288 + ocg * 4];
                T5(0, x00); T5(1, x01); T5(2, x02);
                T5(3, x10); T5(4, x11); T5(5, x12);
                T5(6, x20); T5(7, x21); T5(8, x22);
            }
            h3s[(ocg*4+0)*80 + pos] = f2bf(lrelu(a0));
            h3s[(ocg*4+1)*80 + pos] = f2bf(lrelu(a1));
            h3s[(ocg*4+2)*80 + pos] = f2bf(lrelu(a2));
            h3s[(ocg*4+3)*80 + pos] = f2bf(lrelu(a3));
        }
#undef T5
    }
    __syncthreads();

    // ---- copy stage-6 weights (wp3, row stride 324 to spread banks) ----
    {
        float* wA = (float*)(smem + O_WP3A);
        float* wB = (float*)(smem + O_WP3B);
        float* bp3s = (float*)(smem + O_BP3);
        for (int oc = wave; oc < 32; oc += 8) {
            float* dst = (oc < 16) ? (wA + oc * 324) : (wB + (oc - 16) * 324);
            const float* src = wp3 + oc * 320;
            for (int j = lane; j < 320; j += 64) dst[j] = src[j];
        }
        if (tid < 32) bp3s[tid] = bp3[tid];
    }
    __syncthreads();

    // ---- 6) pool3 (5x2 / (5,2), 32->32) -> fv[256] ----
    {
        const float* bp3s = (const float*)(smem + O_BP3);

#define T6(k, xv) a = __builtin_fmaf(wrow[ic * 10 + (k)], (xv), a)

        if (tid < 256) {
            const int oc = tid >> 3, pos = tid & 7;
            const int pr = pos >> 2, pc = pos & 3;
            const float* wrow = (oc < 16)
                ? (const float*)(smem + O_WP3A) + oc * 324
                : (const float*)(smem + O_WP3B) + (oc - 16) * 324;
            float a = bp3s[oc];
            #pragma unroll 1
            for (int ic = 0; ic < 32; ic++) {
                const unsigned short* hb = &h3s[ic * 80 + 5 * pr * 8 + 2 * pc];
                unsigned int u0 = *(const unsigned int*)(hb + 0);
                unsigned int u1 = *(const unsigned int*)(hb + 8);
                unsigned int u2 = *(const unsigned int*)(hb + 16);
                unsigned int u3 = *(const unsigned int*)(hb + 24);
                unsigned int u4 = *(const unsigned int*)(hb + 32);
                T6(0, bflo(u0)); T6(1, bfhi(u0));
                T6(2, bflo(u1)); T6(3, bfhi(u1));
                T6(4, bflo(u2)); T6(5, bfhi(u2));
                T6(6, bflo(u3)); T6(7, bfhi(u3));
                T6(8, bflo(u4)); T6(9, bfhi(u4));
            }
            fv[oc * 8 + pos] = a;                   // flatten [32][2][4]
        }
#undef T6
    }
    __syncthreads();

    // ---- copy stage-7 weights ----
    {
        float* wmus = (float*)(smem + O_WMU);
        float* wlvs = (float*)(smem + O_WLV);
        float* bmus = (float*)(smem + O_BMU);
        float* blvs = (float*)(smem + O_BLV);
        for (int i = tid; i < 1792; i += NT) wmus[i] = wmu[i];
        for (int i = tid; i < 1792; i += NT) wlvs[i] = wlv[i];
        if (tid < 7) bmus[tid] = bmu[tid];
        if (tid < 7) blvs[tid] = blv[tid];
    }
    __syncthreads();

    // ---- 7) heads ----
    {
        const float* wmus = (const float*)(smem + O_WMU);
        const float* wlvs = (const float*)(smem + O_WLV);
        const float* bmus = (const float*)(smem + O_BMU);
        const float* blvs = (const float*)(smem + O_BLV);
        if (wave < 7) {
            const int j = wave;
            #pragma unroll
            for (int head = 0; head < 2; head++) {
                const float* W = head ? wlvs : wmus;
                float s = 0.f;
                #pragma unroll
                for (int q = 0; q < 4; q++) {
                    int k = lane + 64 * q;
                    s = __builtin_fmaf(fv[k], W[j * 256 + k], s);
                }
                #pragma unroll
                for (int m = 1; m < 64; m <<= 1) s += __shfl_xor(s, m);
                if (lane == 0) {
                    float r = s + (head ? blvs[j] : bmus[j]);
                    if (head) r = fminf(fmaxf(r, -5.f), 0.f);
                    out[head * 28672 + b * 7 + j] = r;
                }
            }
        }
    }
}

extern "C" void kernel_launch(void* const* d_in, const int* in_sizes, int n_in,
                              void* d_out, int out_size, void* d_ws, size_t ws_size,
                              hipStream_t stream) {
    const float* x   = (const float*)d_in[0];
    const float* w1  = (const float*)d_in[1];
    const float* b1  = (const float*)d_in[2];
    const float* w2  = (const float*)d_in[3];
    const float* b2  = (const float*)d_in[4];
    const float* w3  = (const float*)d_in[5];
    const float* b3  = (const float*)d_in[6];
    const float* wp1 = (const float*)d_in[7];
    const float* bp1 = (const float*)d_in[8];
    const float* wp2 = (const float*)d_in[9];
    const float* bp2 = (const float*)d_in[10];
    const float* wp3 = (const float*)d_in[11];
    const float* bp3 = (const float*)d_in[12];
    const float* wmu = (const float*)d_in[13];
    const float* bmu = (const float*)d_in[14];
    const float* wlv = (const float*)d_in[15];
    const float* blv = (const float*)d_in[16];
    float* out = (float*)d_out;

    hipLaunchKernelGGL(vae_encoder_kernel, dim3(4096), dim3(512), 0, stream,
                       x, w1, b1, w2, b2, w3, b3, wp1, bp1, wp2, bp2, wp3, bp3,
                       wmu, bmu, wlv, blv, out);
}